// Round 1
// 550.805 us; speedup vs baseline: 1.1041x; 1.1041x over previous
//
#include <hip/hip_runtime.h>
#include <math.h>

#define HW 12544   // 112*112
#define IMW 112

// async global->LDS, 16B per lane: LDS dest = uniform base + lane*16
#define GLOAD_LDS16(gp, lp) __builtin_amdgcn_global_load_lds( \
    (const __attribute__((address_space(1))) void*)(gp),      \
    (__attribute__((address_space(3))) void*)(lp), 16, 0, 0)

// numpy pairwise add.reduce (n=16) over squares, then norm clamp — bitwise np.linalg.norm
__device__ __forceinline__ float np_norm16(const float* a) {
    float q[16];
    #pragma unroll
    for (int i = 0; i < 16; ++i) q[i] = __fmul_rn(a[i], a[i]);
    float r0 = __fadd_rn(q[0], q[8]),  r1 = __fadd_rn(q[1], q[9]);
    float r2 = __fadd_rn(q[2], q[10]), r3 = __fadd_rn(q[3], q[11]);
    float r4 = __fadd_rn(q[4], q[12]), r5 = __fadd_rn(q[5], q[13]);
    float r6 = __fadd_rn(q[6], q[14]), r7 = __fadd_rn(q[7], q[15]);
    float s = __fadd_rn(__fadd_rn(__fadd_rn(r0, r1), __fadd_rn(r2, r3)),
                        __fadd_rn(__fadd_rn(r4, r5), __fadd_rn(r6, r7)));
    return fmaxf(__fsqrt_rn(s), 1e-12f);
}

__global__ __launch_bounds__(256, 4)
void lc_fused(const float* __restrict__ x,
              const float* __restrict__ fw, const float* __restrict__ fb,
              const float* __restrict__ vw, const float* __restrict__ vb,
              const float* __restrict__ pw, const float* __restrict__ pb,
              const float* __restrict__ alpha, const float* __restrict__ beta,
              float* __restrict__ out)
{
    // LDS union U (8192 floats = 32 KB), phase-aliased:
    //  P1: fw_s[2048]=U[0:2048] | vw_s[2048]=U[2048:4096] | xs[16*256]=U[4096:8192]
    //  P2-P5: f_s[256*16]=U[0:4096] | cent_s[784]=U[4096:4880] | ncf_s[784]=U[4880:5664]
    //         vcent_s[784]=U[5664:6448] | simsum_s[49]=U[6448:6497]
    //  P6-P7: Pagg_s[128][49]=U[0:6272]  (two 128-channel halves)
    __shared__ __attribute__((aligned(16))) float U[8192];
    __shared__ __attribute__((aligned(16))) float agg_s[784];
    __shared__ __attribute__((aligned(16))) float pb_s[256];
    __shared__ __attribute__((aligned(16))) float simv_s[256];
    __shared__ __attribute__((aligned(16))) int   bidx_s[256];

    float* fw_s    = U;
    float* vw_s    = U + 2048;
    float* xs      = U + 4096;
    float* f_s     = U;
    float* cent_s  = U + 4096;
    float* ncf_s   = U + 4880;
    float* vcent_s = U + 5664;
    float* simsum_s= U + 6448;
    float* Pagg_s  = U;

    const int t    = threadIdx.x;
    const int wave = t >> 6, lane = t & 63;
    const int py = t >> 4, px = t & 15;
    const int b  = blockIdx.x;
    const int batch = b / 49;
    const int rr = b % 49;
    const int gi = rr / 7, gj = rr % 7;
    const int row = gi*16 + py, col = gj*16 + px;

    // ---- P0: stage weights (float4), zero agg ----
    for (int i = t; i < 512; i += 256) {
        ((float4*)fw_s)[i] = ((const float4*)fw)[i];
        ((float4*)vw_s)[i] = ((const float4*)vw)[i];
    }
    pb_s[t] = pb[t];
    for (int i = t; i < 784; i += 256) agg_s[i] = 0.f;
    // no barrier needed: first in-loop barrier below orders these writes

    // ---- P1: f (bitwise-np fp32: ascending c, separate mul/add, bias last);
    //          v (fast fmaf). x staged through LDS via global_load_lds,
    //          16 channels (8 f + 8 v) per chunk. Values identical to the
    //          old per-thread scalar loads -> facc chain stays bit-exact.
    // lane l stages quad (row=l>>2, cols (l&3)*4..+3) of one channel tile.
    const float* xbase = x + (size_t)batch*256*HW
                       + (size_t)(gi*16 + (lane >> 2))*IMW + gj*16 + (lane & 3)*4;

    float facc[16], vacc[16];
    #pragma unroll
    for (int o = 0; o < 16; ++o) { facc[o] = 0.f; vacc[o] = vb[o]; }

    for (int ch = 0; ch < 16; ++ch) {
        // stage: wave w loads channels sc = 4w..4w+3 of this chunk
        #pragma unroll
        for (int k = 0; k < 4; ++k) {
            const int sc = (wave << 2) + k;                      // 0..15, wave-uniform
            const int gc = (sc < 8) ? (ch*8 + sc)                // f channels
                                    : (120 + ch*8 + sc);         // 128 + ch*8 + (sc-8)
            GLOAD_LDS16(xbase + (size_t)gc*HW, xs + (sc << 8));
        }
        __syncthreads();   // drains vmcnt -> staged tiles visible

        #pragma unroll
        for (int half = 0; half < 2; ++half) {
            const int c4 = (ch << 1) + half;
            const float* xf = xs + ((half*4) << 8) + t;
            const float* xv = xs + 2048 + ((half*4) << 8) + t;
            const float x0 = xf[0], x1 = xf[256], x2 = xf[512], x3 = xf[768];
            const float y0 = xv[0], y1 = xv[256], y2 = xv[512], y3 = xv[768];
            #pragma unroll
            for (int o = 0; o < 16; ++o) {
                const float* ar = fw_s + o*128 + c4*4;
                float s = facc[o];
                s = __fadd_rn(s, __fmul_rn(ar[0], x0));
                s = __fadd_rn(s, __fmul_rn(ar[1], x1));
                s = __fadd_rn(s, __fmul_rn(ar[2], x2));
                s = __fadd_rn(s, __fmul_rn(ar[3], x3));
                facc[o] = s;
                const float* cr = vw_s + o*128 + c4*4;
                vacc[o] = fmaf(cr[3], y3, fmaf(cr[2], y2, fmaf(cr[1], y1, fmaf(cr[0], y0, vacc[o]))));
            }
        }
        __syncthreads();   // before next chunk overwrites xs
    }
    #pragma unroll
    for (int o = 0; o < 16; ++o) facc[o] = __fadd_rn(facc[o], fb[o]);

    // zero vcent/simsum (aliased with xs, which is now dead)
    for (int i = t; i < 784; i += 256) vcent_s[i] = 0.f;
    if (t < 49) simsum_s[t] = 0.f;
    __syncthreads();

    // ---- P2a: stage f to LDS + v pooling (fp32 atomics, value path) ----
    {
        float* fr = f_s + t*16;
        #pragma unroll
        for (int o = 0; o < 16; ++o) fr[o] = facc[o];
    }
    {
        const int   wss[7] = {0,2,4,6,9,11,13};
        const int   wee[7] = {3,5,7,10,12,14,16};
        const float wiv[7] = {1.f/3.f,1.f/3.f,1.f/3.f,0.25f,1.f/3.f,1.f/3.f,1.f/3.f};
        for (int i = 0; i < 7; ++i) {
            if (py < wss[i] || py >= wee[i]) continue;
            for (int j = 0; j < 7; ++j) {
                if (px < wss[j] || px >= wee[j]) continue;
                const float sc = wiv[i]*wiv[j];
                float* vb2 = vcent_s + (i*7+j)*16;
                #pragma unroll
                for (int o = 0; o < 16; ++o) atomicAdd(vb2 + o, vacc[o]*sc);
            }
        }
    }
    __syncthreads();

    // ---- P2b: centers, bitwise-np: per-term (Pw*f)*Ph, w-outer h-inner ascending ----
    {
        const int   wss[7] = {0,2,4,6,9,11,13};
        const int   wee[7] = {3,5,7,10,12,14,16};
        const float wiv[7] = {1.f/3.f,1.f/3.f,1.f/3.f,0.25f,1.f/3.f,1.f/3.f,1.f/3.f};
        for (int T = t; T < 784; T += 256) {
            int m = T >> 4, o = T & 15;
            int i = m / 7, j = m % 7;
            float pwv = wiv[i], phv = wiv[j];
            float s = 0.f;
            for (int r = wss[i]; r < wee[i]; ++r)
                for (int cc = wss[j]; cc < wee[j]; ++cc)
                    s = __fadd_rn(s, __fmul_rn(__fmul_rn(pwv, f_s[(r*16 + cc)*16 + o]), phv));
            cent_s[T] = s;
        }
    }
    __syncthreads();

    // ---- P3: normalize centers (bitwise np.linalg.norm + divide) ----
    if (t < 49) {
        float rowv[16];
        #pragma unroll
        for (int o = 0; o < 16; ++o) rowv[o] = cent_s[t*16 + o];
        float n = np_norm16(rowv);
        #pragma unroll
        for (int o = 0; o < 16; ++o) ncf_s[t*16 + o] = __fdiv_rn(rowv[o], n);
    }
    __syncthreads();

    // ---- P4: fp32 sim (bitwise-ish) + first-max argmax; value-path aggregation ----
    float nff[16];
    {
        float n = np_norm16(facc);
        #pragma unroll
        for (int o = 0; o < 16; ++o) nff[o] = __fdiv_rn(facc[o], n);
    }
    const float al = alpha[0], be = beta[0];
    float best = -1.0f; int bidx = 0;
    for (int m = 0; m < 49; ++m) {
        const float* cm = ncf_s + m*16;
        float s = 0.f;
        #pragma unroll
        for (int o = 0; o < 16; ++o) s = __fadd_rn(s, __fmul_rn(cm[o], nff[o]));
        float z = __fadd_rn(be, __fmul_rn(al, s));
        float sim = __fdiv_rn(1.0f, __fadd_rn(1.0f, expf(-z)));
        if (sim > best) { best = sim; bidx = m; }   // first-max == np.argmax
    }
    const float simv = best;
    simv_s[t] = simv;
    bidx_s[t] = bidx;
    atomicAdd(&simsum_s[bidx], simv);
    {
        float* ab = agg_s + bidx*16;
        #pragma unroll
        for (int o = 0; o < 16; ++o) atomicAdd(ab + o, simv*vacc[o]);
    }
    __syncthreads();

    // ---- P5: finalize agg ----
    for (int T = t; T < 784; T += 256) {
        int m = T >> 4;
        agg_s[T] = (agg_s[T] + vcent_s[T]) / (simsum_s[m] + 1.0f);
    }
    __syncthreads();   // U reusable for Pagg halves

    // ---- P6/P7 in two 128-channel halves (Pagg_s = 128x49 floats) ----
    float* out_tile = out + (size_t)batch*256*HW + (size_t)(gi*16)*IMW + gj*16;
    // P7 mapping: wave 'og' handles 32 channels; lane q handles pixel quad
    // (row q>>2, cols (q&3)*4..+3) -> float4 stores, fully coalesced.
    float* op4 = out_tile + (lane >> 2)*IMW + (lane & 3)*4;
    const float4 sv4 = *(const float4*)(simv_s + (lane << 2));
    const int4   bi4 = *(const int4*)  (bidx_s + (lane << 2));

    const int oc6 = t >> 1;                 // 0..127: two threads per output chan
    const int m0  = (t & 1) ? 25 : 0;
    const int m1  = (t & 1) ? 49 : 25;

    #pragma unroll
    for (int half = 0; half < 2; ++half) {
        // P6: Pagg[oc][m] = pw[half*128+oc,:] . agg[m,:]  (same fmaf chain as before)
        {
            const int o = (half << 7) + oc6;
            const float4* pg = (const float4*)(pw + o*16);
            const float4 q0 = pg[0], q1 = pg[1], q2 = pg[2], q3 = pg[3];
            float* pr = Pagg_s + oc6*49;
            for (int m = m0; m < m1; ++m) {
                const float4* am = (const float4*)(agg_s + m*16);
                float4 a0 = am[0], a1 = am[1], a2 = am[2], a3 = am[3];
                float d;
                d = q0.x*a0.x;
                d = fmaf(q0.y,a0.y,d); d = fmaf(q0.z,a0.z,d); d = fmaf(q0.w,a0.w,d);
                d = fmaf(q1.x,a1.x,d); d = fmaf(q1.y,a1.y,d); d = fmaf(q1.z,a1.z,d);
                d = fmaf(q1.w,a1.w,d); d = fmaf(q2.x,a2.x,d); d = fmaf(q2.y,a2.y,d);
                d = fmaf(q2.z,a2.z,d); d = fmaf(q2.w,a2.w,d); d = fmaf(q3.x,a3.x,d);
                d = fmaf(q3.y,a3.y,d); d = fmaf(q3.z,a3.z,d); d = fmaf(q3.w,a3.w,d);
                pr[m] = d;
            }
        }
        __syncthreads();
        // P7: out[o, pixel] = simv*Pagg[o][bidx] + pb[o], float4 over pixel quads
        #pragma unroll 8
        for (int k = 0; k < 32; ++k) {
            const int oc = (wave << 5) + k;
            const int o  = (half << 7) + oc;
            const float* pr = Pagg_s + oc*49;
            const float pbo = pb_s[o];
            float4 r;
            r.x = fmaf(sv4.x, pr[bi4.x], pbo);
            r.y = fmaf(sv4.y, pr[bi4.y], pbo);
            r.z = fmaf(sv4.z, pr[bi4.z], pbo);
            r.w = fmaf(sv4.w, pr[bi4.w], pbo);
            *(float4*)(op4 + (size_t)o*HW) = r;
        }
        __syncthreads();   // before next half overwrites Pagg
    }
}

extern "C" void kernel_launch(void* const* d_in, const int* in_sizes, int n_in,
                              void* d_out, int out_size, void* d_ws, size_t ws_size,
                              hipStream_t stream) {
    const float* x  = (const float*)d_in[0];
    const float* fw = (const float*)d_in[1];
    const float* fb = (const float*)d_in[2];
    const float* vw = (const float*)d_in[3];
    const float* vb = (const float*)d_in[4];
    const float* pw = (const float*)d_in[5];
    const float* pb = (const float*)d_in[6];
    const float* al = (const float*)d_in[7];
    const float* be = (const float*)d_in[8];
    float* out = (float*)d_out;

    dim3 grid(784), block(256);
    hipLaunchKernelGGL(lc_fused, grid, block, 0, stream,
                       x, fw, fb, vw, vb, pw, pb, al, be, out);
}